// Round 9
// baseline (205.219 us; speedup 1.0000x reference)
//
#include <hip/hip_runtime.h>
#include <hip/hip_bf16.h>
#include <stdint.h>

// Problem constants (GQA: D=1024, 16 heads, 4 groups, hd=64)
#define D_MODEL 1024
#define T_LEN   2048
#define BATCH   2
#define N_HEADS 16
#define KV_DIM  256
#define QKV_N   1536              // 1024 + 256 + 256 fused projection width
#define M_ROWS  (BATCH * T_LEN)   // 4096

typedef unsigned short u16;
typedef __bf16 bf16x8 __attribute__((ext_vector_type(8)));
typedef __bf16 bf16x2 __attribute__((ext_vector_type(2)));
typedef float  f32x4  __attribute__((ext_vector_type(4)));

__device__ __forceinline__ u16 f2b(float f) {
    uint32_t u = __builtin_bit_cast(uint32_t, f);
    u += 0x7FFFu + ((u >> 16) & 1u);   // round-to-nearest-even
    return (u16)(u >> 16);
}

// pack two f32 -> two bf16 in one u32 (lo = a, hi = b)
__device__ __forceinline__ uint32_t pk_bf16(float a, float b) {
#if __has_builtin(__builtin_amdgcn_cvt_pk_bf16_f32)
    bf16x2 v = __builtin_amdgcn_cvt_pk_bf16_f32(a, b);
    return __builtin_bit_cast(uint32_t, v);
#else
    return (uint32_t)f2b(a) | ((uint32_t)f2b(b) << 16);
#endif
}

// async global->LDS, 16B per lane; LDS dest = wave-uniform base + lane*16
__device__ __forceinline__ void gl_lds16(const void* g, void* l) {
    __builtin_amdgcn_global_load_lds(g, l, 16, 0, 0);
}

// ---------------------------------------------------------------------------
// prep: fp32->bf16 convert of x (blocks 0..2047) + all-weight transpose/cvt
// (blocks 2048..4607). One launch.
// ---------------------------------------------------------------------------
__global__ __launch_bounds__(256) void prep(
    const float* __restrict__ x,
    const float* __restrict__ Wq, const float* __restrict__ Wk,
    const float* __restrict__ Wv, const float* __restrict__ Wo,
    u16* __restrict__ xb, u16* __restrict__ WcatT, u16* __restrict__ WoT)
{
    __shared__ u16 tile[32][33];
    int id = blockIdx.x;
    int tid = threadIdx.x;
    if (id < 2048) {
        int i = (id * 256 + tid) * 8;
        float4 a = *(const float4*)&x[i];
        float4 c = *(const float4*)&x[i + 4];
        u16 r[8] = { f2b(a.x), f2b(a.y), f2b(a.z), f2b(a.w),
                     f2b(c.x), f2b(c.y), f2b(c.z), f2b(c.w) };
        *(uint4*)&xb[i] = *(const uint4*)r;
        return;
    }
    int t = id - 2048;
    int bx = t % 80;
    int k0 = (t / 80) * 32;
    const float* src; u16* dst; int N, n0;
    if (bx < 32)       { src = Wq; dst = WcatT;                   N = 1024; n0 = bx * 32; }
    else if (bx < 40)  { src = Wk; dst = WcatT + 1024 * 1024;     N = 256;  n0 = (bx - 32) * 32; }
    else if (bx < 48)  { src = Wv; dst = WcatT + 1280 * 1024;     N = 256;  n0 = (bx - 40) * 32; }
    else               { src = Wo; dst = WoT;                     N = 1024; n0 = (bx - 48) * 32; }
    for (int i = 0; i < 4; ++i) {
        int idx = tid + i * 256;
        int r = idx >> 5, c = idx & 31;
        tile[r][c] = f2b(src[(size_t)(k0 + r) * N + (n0 + c)]);
    }
    __syncthreads();
    for (int i = 0; i < 4; ++i) {
        int idx = tid + i * 256;
        int r = idx >> 5, c = idx & 31;   // r: n-local, c: k-local
        dst[(size_t)(n0 + r) * 1024 + (k0 + c)] = tile[c][r];
    }
}

// ---------------------------------------------------------------------------
// Fused QKV GEMM, m97-style 128x128 tile (16 MFMA : 8 gl_lds per wave-iter).
// Q -> Qb[4096x1024] PRE-SCALED (log2 domain). K/V -> fragment-major packed
// layouts (verified round 8):
//   Kpack[(b,g)][t64][kk][ntk][lane=quad*16+l15][8e]
//   Vpack[(b,g)][t64][kkp][dt][lane=quad*16+l15][8e]
// ---------------------------------------------------------------------------
__global__ __launch_bounds__(256) void gemm_qkv(
    const u16* __restrict__ A, const u16* __restrict__ BT,
    const float* __restrict__ bq, const float* __restrict__ bk,
    const float* __restrict__ bv, u16* __restrict__ Qb,
    u16* __restrict__ Kpack, u16* __restrict__ Vpack)
{
    constexpr int K = 1024;
    constexpr float SCALE = 0.125f * 1.44269504088896f;
    __shared__ __align__(16) u16 As[128 * 64];
    __shared__ __align__(16) u16 Bs[128 * 64];

    int tid  = threadIdx.x;
    int lane = tid & 63, w = tid >> 6;
    int wm = w & 1, wn = w >> 1;
    int quad = lane >> 4, l15 = lane & 15;
    int m0 = blockIdx.y * 128, n0 = blockIdx.x * 128;
    int lr = lane >> 3, lc = (lane & 7) * 8;

    f32x4 acc[4][4] = {};

    for (int k0 = 0; k0 < K; k0 += 64) {
        for (int t = 0; t < 4; ++t) {
            int rb = w * 32 + t * 8;
            gl_lds16(&A[(size_t)(m0 + rb + lr) * K + k0 + lc], &As[rb * 64]);
            gl_lds16(&BT[(size_t)(n0 + rb + lr) * K + k0 + lc], &Bs[rb * 64]);
        }
        __syncthreads();
        for (int kk = 0; kk < 64; kk += 32) {
            bf16x8 a[4], b[4];
            for (int i = 0; i < 4; ++i)
                a[i] = *(const bf16x8*)&As[(wm * 64 + i * 16 + l15) * 64 + kk + quad * 8];
            for (int j = 0; j < 4; ++j)
                b[j] = *(const bf16x8*)&Bs[(wn * 64 + j * 16 + l15) * 64 + kk + quad * 8];
            for (int i = 0; i < 4; ++i)
                for (int j = 0; j < 4; ++j)
                    acc[i][j] = __builtin_amdgcn_mfma_f32_16x16x32_bf16(
                        a[i], b[j], acc[i][j], 0, 0, 0);
        }
        __syncthreads();
    }

    for (int j = 0; j < 4; ++j) {
        int col = n0 + wn * 64 + j * 16 + l15;
        float bj = (col < 1024) ? bq[col] : (col < 1280) ? bk[col - 1024] : bv[col - 1280];
        for (int i = 0; i < 4; ++i) {
            int rowb = m0 + wm * 64 + i * 16 + quad * 4;   // 4 consecutive rows
            int bb = rowb >> 11, keyloc = rowb & 2047;
            int t64 = keyloc >> 6;
            if (col < 1024) {
                for (int r = 0; r < 4; ++r)
                    Qb[(size_t)(rowb + r) * 1024 + col] =
                        f2b((acc[i][j][r] + bj) * SCALE);
            } else if (col < 1280) {
                int d = col - 1024; int g = d >> 6; d &= 63;
                int kk = d >> 5, qd = (d >> 3) & 3, e = d & 7;
                int ntk = (keyloc >> 4) & 3, l15k = keyloc & 15;
                size_t base = ((((size_t)(bb * 4 + g) * 32 + t64) * 2 + kk) * 4
                               + ntk) * 512 + qd * 128 + l15k * 8 + e;
                for (int r = 0; r < 4; ++r)
                    Kpack[base + r * 8] = f2b(acc[i][j][r] + bj);
            } else {
                int d = col - 1280; int g = d >> 6; d &= 63;
                int dt = d >> 4, l15v = d & 15;
                int kkp = (keyloc >> 5) & 1, qv = (keyloc >> 3) & 3, e0 = keyloc & 7;
                u16 tmp[4];
                for (int r = 0; r < 4; ++r) tmp[r] = f2b(acc[i][j][r] + bj);
                size_t base = ((((size_t)(bb * 4 + g) * 32 + t64) * 2 + kkp) * 4
                               + dt) * 512 + (qv * 16 + l15v) * 8 + e0;
                *(uint64_t*)&Vpack[base] = *(const uint64_t*)tmp;
            }
        }
    }
}

// ---------------------------------------------------------------------------
// Out-proj GEMM, m97-style 128x128 tile: out[M x 1024](fp32) = AO*WoT^T + bo.
// ---------------------------------------------------------------------------
__global__ __launch_bounds__(256) void gemm_out(
    const u16* __restrict__ A, const u16* __restrict__ BT,
    const float* __restrict__ bias, float* __restrict__ C)
{
    constexpr int K = 1024, N = 1024;
    __shared__ __align__(16) u16 As[128 * 64];
    __shared__ __align__(16) u16 Bs[128 * 64];

    int tid  = threadIdx.x;
    int lane = tid & 63, w = tid >> 6;
    int wm = w & 1, wn = w >> 1;
    int quad = lane >> 4, l15 = lane & 15;
    int m0 = blockIdx.y * 128, n0 = blockIdx.x * 128;
    int lr = lane >> 3, lc = (lane & 7) * 8;

    f32x4 acc[4][4] = {};

    for (int k0 = 0; k0 < K; k0 += 64) {
        for (int t = 0; t < 4; ++t) {
            int rb = w * 32 + t * 8;
            gl_lds16(&A[(size_t)(m0 + rb + lr) * K + k0 + lc], &As[rb * 64]);
            gl_lds16(&BT[(size_t)(n0 + rb + lr) * K + k0 + lc], &Bs[rb * 64]);
        }
        __syncthreads();
        for (int kk = 0; kk < 64; kk += 32) {
            bf16x8 a[4], b[4];
            for (int i = 0; i < 4; ++i)
                a[i] = *(const bf16x8*)&As[(wm * 64 + i * 16 + l15) * 64 + kk + quad * 8];
            for (int j = 0; j < 4; ++j)
                b[j] = *(const bf16x8*)&Bs[(wn * 64 + j * 16 + l15) * 64 + kk + quad * 8];
            for (int i = 0; i < 4; ++i)
                for (int j = 0; j < 4; ++j)
                    acc[i][j] = __builtin_amdgcn_mfma_f32_16x16x32_bf16(
                        a[i], b[j], acc[i][j], 0, 0, 0);
        }
        __syncthreads();
    }

    for (int j = 0; j < 4; ++j) {
        int col = n0 + wn * 64 + j * 16 + l15;
        float bj = bias[col];
        for (int i = 0; i < 4; ++i) {
            int rowb = m0 + wm * 64 + i * 16 + quad * 4;
            for (int r = 0; r < 4; ++r)
                C[(size_t)(rowb + r) * N + col] = acc[i][j][r] + bj;
        }
    }
}

// ---------------------------------------------------------------------------
// Flash attention v5 (causal, GQA): barrier-free, 16-row q-strips, 1024
// blocks (4/CU). Block = (b, g, strip); 4 independent waves = the group's 4
// heads. K/V fragments loaded directly from global fragment-packed layouts
// (coalesced lane*16B, L2-resident). P via wave-private LDS (DS in-order).
// Fixed-max softmax, log2 domain (Q pre-scaled), mask on diagonal tile only.
// Co-residency balance: sets {idx, idx+32, idx+64, idx+96} (same (b,g)=gid&7,
// same XCD) map to strips {m, 63-m, 64+m, 127-m} -> constant 66 iter sum.
// ---------------------------------------------------------------------------
__global__ __launch_bounds__(256, 4) void attn_kernel(
    const u16* __restrict__ Qb,     // [B*T, 1024] bf16, pre-scaled
    const u16* __restrict__ Kpack,  // fragment-packed K
    const u16* __restrict__ Vpack,  // fragment-packed V
    u16* __restrict__ AO)           // [B*T, 1024] bf16
{
    constexpr int LDP = 72;   // P row stride (u16)
    __shared__ __align__(16) u16 Ps[4][16 * LDP];   // wave-private P tiles

    int tid  = threadIdx.x;
    int lane = tid & 63, w = tid >> 6;
    int quad = lane >> 4, l15 = lane & 15;

    int gid = blockIdx.x;
    int b = gid & 1, g = (gid >> 1) & 3;
    int idx = gid >> 3;                  // 0..127
    int m = idx & 31, qsel = idx >> 5;
    int strip = (qsel == 0) ? m : (qsel == 1) ? (63 - m)
              : (qsel == 2) ? (64 + m) : (127 - m);
    int head = g * 4 + w;
    int q0 = strip * 16;
    int iters = (strip >> 2) + 1;        // k-tiles of 64 keys

    const u16* Qp = Qb + ((size_t)b * T_LEN + q0) * 1024 + head * 64;
    const u16* Kp = Kpack + (size_t)(b * 4 + g) * 131072 + (size_t)lane * 8;
    const u16* Vp = Vpack + (size_t)(b * 4 + g) * 131072 + (size_t)lane * 8;
    u16*       Op = AO + ((size_t)b * T_LEN + q0) * D_MODEL + head * 64;
    u16* Pw = Ps[w];

    // Q fragments (loop-invariant): B-frag Q[n=qrow][k=d]
    bf16x8 Qfrag[2];
    #pragma unroll
    for (int kk = 0; kk < 2; ++kk)
        Qfrag[kk] = *(const bf16x8*)
            &Qp[(size_t)l15 * 1024 + kk * 32 + quad * 8];

    f32x4 o[4] = {};
    float lsum = 0.f;

    for (int tg = 0; tg < iters; ++tg) {
        bool diag = (tg == iters - 1);

        // K fragments straight from global (coalesced 1KB per load)
        const u16* kb = Kp + (size_t)tg * 4096;
        bf16x8 aK[2][4];
        #pragma unroll
        for (int kk = 0; kk < 2; ++kk)
            #pragma unroll
            for (int ntk = 0; ntk < 4; ++ntk)
                aK[kk][ntk] = *(const bf16x8*)(kb + (kk * 4 + ntk) * 512);

        // S^T = K * Q^T; D: row(quad*4+reg)=key, col(l15)=qrow
        f32x4 s[4] = {};
        #pragma unroll
        for (int kk = 0; kk < 2; ++kk) {
            bf16x8 bQ = Qfrag[kk];
            #pragma unroll
            for (int ntk = 0; ntk < 4; ++ntk)
                s[ntk] = __builtin_amdgcn_mfma_f32_16x16x32_bf16(
                    aK[kk][ntk], bQ, s[ntk], 0, 0, 0);
        }

        // exp2 (log2 domain) + causal mask (diag tile) + l + packed P
        int qrow = q0 + l15;
        #pragma unroll
        for (int ntk = 0; ntk < 4; ++ntk) {
            float p0, p1, p2, p3;
            if (diag) {
                int key = tg * 64 + ntk * 16 + quad * 4;
                p0 = (key + 0 <= qrow) ? exp2f(s[ntk][0]) : 0.f;
                p1 = (key + 1 <= qrow) ? exp2f(s[ntk][1]) : 0.f;
                p2 = (key + 2 <= qrow) ? exp2f(s[ntk][2]) : 0.f;
                p3 = (key + 3 <= qrow) ? exp2f(s[ntk][3]) : 0.f;
            } else {
                p0 = exp2f(s[ntk][0]);
                p1 = exp2f(s[ntk][1]);
                p2 = exp2f(s[ntk][2]);
                p3 = exp2f(s[ntk][3]);
            }
            lsum += (p0 + p1) + (p2 + p3);
            uint2 pv;
            pv.x = pk_bf16(p0, p1);
            pv.y = pk_bf16(p2, p3);
            *(uint2*)&Pw[l15 * LDP + ntk * 16 + quad * 4] = pv;
        }

        // O += P V : V fragments straight from global; aP from wave-private P
        const u16* vb = Vp + (size_t)tg * 4096;
        #pragma unroll
        for (int kkp = 0; kkp < 2; ++kkp) {
            bf16x8 aP = *(const bf16x8*)&Pw[l15 * LDP + kkp * 32 + quad * 8];
            #pragma unroll
            for (int dt = 0; dt < 4; ++dt) {
                bf16x8 bV = *(const bf16x8*)(vb + (kkp * 4 + dt) * 512);
                o[dt] = __builtin_amdgcn_mfma_f32_16x16x32_bf16(
                    aP, bV, o[dt], 0, 0, 0);
            }
        }
    }

    // epilogue: reduce l across quads (once), normalize, store
    float l = lsum;
    l += __shfl_xor(l, 16, 64);
    l += __shfl_xor(l, 32, 64);
    float linv = 1.0f / l;                 // for qrow = q0 + l15
    float li[4];
    #pragma unroll
    for (int r = 0; r < 4; ++r)
        li[r] = __shfl(linv, quad * 4 + r, 64);   // qrow q0 + quad*4 + r
    #pragma unroll
    for (int dt = 0; dt < 4; ++dt)
        #pragma unroll
        for (int r = 0; r < 4; ++r)
            Op[(size_t)(quad * 4 + r) * D_MODEL + dt * 16 + l15] =
                f2b(o[dt][r] * li[r]);
}

// ---------------------------------------------------------------------------
extern "C" void kernel_launch(void* const* d_in, const int* in_sizes, int n_in,
                              void* d_out, int out_size, void* d_ws, size_t ws_size,
                              hipStream_t stream) {
    const float* x  = (const float*)d_in[0];
    const float* Wq = (const float*)d_in[1];
    const float* bq = (const float*)d_in[2];
    const float* Wk = (const float*)d_in[3];
    const float* bk = (const float*)d_in[4];
    const float* Wv = (const float*)d_in[5];
    const float* bv = (const float*)d_in[6];
    const float* Wo = (const float*)d_in[7];
    const float* bo = (const float*)d_in[8];
    float* out = (float*)d_out;

    u16* ws    = (u16*)d_ws;
    u16* xb    = ws;  ws += (size_t)M_ROWS * 1024;   // x bf16; reused as AO
    u16* WcatT = ws;  ws += (size_t)QKV_N * 1024;
    u16* WoT   = ws;  ws += 1024 * 1024;
    u16* Qb    = ws;  ws += (size_t)M_ROWS * 1024;
    u16* Kpack = ws;  ws += (size_t)M_ROWS * KV_DIM;
    u16* Vpack = ws;  ws += (size_t)M_ROWS * KV_DIM;
    u16* AO    = xb;                                  // alias: xb dead after gemm_qkv
    // total ws use: ~25 MB

    prep<<<2048 + 2560, 256, 0, stream>>>(x, Wq, Wk, Wv, Wo, xb, WcatT, WoT);
    gemm_qkv<<<dim3(QKV_N / 128, M_ROWS / 128), 256, 0, stream>>>(
        xb, WcatT, bq, bk, bv, Qb, Kpack, Vpack);
    attn_kernel<<<1024, 256, 0, stream>>>(Qb, Kpack, Vpack, AO);
    gemm_out<<<dim3(1024 / 128, M_ROWS / 128), 256, 0, stream>>>(AO, WoT, bo, out);
}